// Round 6
// baseline (2288.357 us; speedup 1.0000x reference)
//
#include <hip/hip_runtime.h>
#include <cstdint>
#include <cstddef>

// ---------------------------------------------------------------------------
// LSTM forward, persistent-kernel design (round 6):
//   grid = 256 WGs = 4 batch-groups(16 rows) x 64 hidden-groups(16 cols)
//   Narrow-flag protocol, refined to shave serial IC-latency segments:
//     - PER-WAVE flags (4 per WG): epilogue wave drains its own h stores and
//       publishes its flag BEFORE barrier2 (removes barrier+tid0 serialization)
//     - PIPELINED 4-deep poll (vmcnt(3) rotation + s_sleep stagger):
//       discovery granularity ~200cy instead of ~RTT(800)
//     - rcp-based sigmoid/tanh (divides off the critical path)
//   ALL 8 waves split BOTH K-halves (128 x-cols + 128 h-cols each).
//   Cross-WG h + flags stay sc0|sc1 cache-BYPASS (coherent at IC, no fences).
//   LDS: 8x4 partial C tiles -> fused epilogue; c-state in registers.
//   Slab-reuse proof: barrier1 orders all 8 waves' polls (flags>=t+1 => every
//   bg WG's step-t h loads RETURNED) before epilogue overwrites slab[t&1].
// ---------------------------------------------------------------------------

typedef short bf16x8 __attribute__((ext_vector_type(8)));
typedef float f32x4  __attribute__((ext_vector_type(4)));
typedef int   i32x4  __attribute__((ext_vector_type(4)));

#define XT_OFF   0ull                 // x^T bf16 [512][64][1024]  = 64 MiB
#define WT_OFF   67108864ull          // W^T bf16 [4096][2048]     = 16 MiB
#define HB_OFF   83886080ull          // h double buffer bf16 [2][64][1024] = 256 KiB
#define CNT_OFF  84148224ull          // 1024 flags, 256B-spaced = 256 KiB
#define WS_NEED  84410368ull

__device__ __forceinline__ unsigned short f2bf(float f) {
  union { float f; unsigned u; } v; v.f = f;
  unsigned r = (v.u + 0x7fffu + ((v.u >> 16) & 1u)) >> 16;   // RNE
  return (unsigned short)r;
}

// x (B,S,I) fp32 -> xT (S,B,I) bf16.  blk = b*512+s, 256 thr x float4
__global__ void k_convert_x(const float* __restrict__ x, unsigned short* __restrict__ xT) {
  const int blk = blockIdx.x;
  const int b = blk >> 9, s = blk & 511;
  const float4 v = ((const float4*)(x + (size_t)blk * 1024))[threadIdx.x];
  ushort4 o;
  o.x = f2bf(v.x); o.y = f2bf(v.y); o.z = f2bf(v.z); o.w = f2bf(v.w);
  ((ushort4*)(xT + ((size_t)s * 64 + b) * 1024))[threadIdx.x] = o;
}

// W [2048][4096] fp32 -> WT [4096][2048] bf16, 64x64 LDS tiles
__global__ void k_convert_W(const float* __restrict__ W, unsigned short* __restrict__ WT) {
  __shared__ float tile[64][65];
  const int bx = blockIdx.x & 31;   // k-tile
  const int by = blockIdx.x >> 5;   // g-tile
  const int k0 = bx << 6, g0 = by << 6;
  for (int i = threadIdx.x; i < 4096; i += 256) {
    const int r = i >> 6, c = i & 63;
    tile[r][c] = W[(size_t)(k0 + r) * 4096 + g0 + c];
  }
  __syncthreads();
  for (int i = threadIdx.x; i < 4096; i += 256) {
    const int g = i >> 6, k = i & 63;
    WT[(size_t)(g0 + g) * 2048 + k0 + k] = f2bf(tile[k][g]);
  }
}

// zero h parity-0 slab (128 KiB) + 256 KiB of flags
__global__ void k_init(unsigned short* __restrict__ hbuf, unsigned int* __restrict__ cnt) {
  const int b = blockIdx.x;
  const size_t i = threadIdx.x;
  if (b < 32) ((uint4*)hbuf)[(size_t)b * 256 + i] = uint4{0u, 0u, 0u, 0u};
  else        ((uint4*)cnt )[(size_t)(b - 32) * 256 + i] = uint4{0u, 0u, 0u, 0u};
}

__global__ __launch_bounds__(512, 1) void lstm_persistent(
    const unsigned short* __restrict__ xT,   // [512][64][1024] bf16
    const unsigned short* __restrict__ WT,   // [4096][2048] bf16
    const float* __restrict__ bias,          // [4096]
    unsigned short* __restrict__ hbuf,       // [2][64][1024] bf16
    unsigned int* __restrict__ cnt,          // 1024 flags, 64-uint (256B) stride
    float* __restrict__ out)                 // outputs(B,S,H) + h_T + c_T
{
  __shared__ float slots[8 * 4 * 320];       // [wave][gate][col*20 + row], 40 KiB

  const int tid  = threadIdx.x;
  const int lane = tid & 63;
  const int wave = tid >> 6;                 // 0..7: 128 x-cols + 128 h-cols each
  const int bg = blockIdx.x & 3;             // batch group (16 rows)
  const int hg = blockIdx.x >> 2;            // hidden group (16 cols)
  const int b0 = bg << 4;
  const int l15 = lane & 15;
  const int l4  = lane >> 4;

  // --- loop-invariant B fragments: 4 gates x (4 x-chunks + 4 h-chunks) ---
  bf16x8 Bf[4][8];
#pragma unroll
  for (int g = 0; g < 4; ++g) {
    const unsigned short* wp =
        WT + (size_t)(g * 1024 + (hg << 4) + l15) * 2048 + l4 * 8;
#pragma unroll
    for (int kc = 0; kc < 4; ++kc)
      Bf[g][kc] = *(const bf16x8*)(wp + wave * 128 + kc * 32);            // x side
#pragma unroll
    for (int kc = 0; kc < 4; ++kc)
      Bf[g][4 + kc] = *(const bf16x8*)(wp + 1024 + wave * 128 + kc * 32); // h side
  }

  // --- per-cell epilogue constants (threads 0..255: cell (row rb, col cc)) ---
  const int cc = tid & 15;
  const int rb = (tid >> 4) & 15;
  float bi = 0.f, bff = 0.f, bgg = 0.f, bo = 0.f;
  if (tid < 256) {
    const int col = (hg << 4) + cc;
    bi  = bias[col];
    bff = bias[1024 + col];
    bgg = bias[2048 + col];
    bo  = bias[3072 + col];
  }
  float c_state = 0.f;
  bool dead = false;                         // latched poll guard; fail fast, no hang

  // flags: producer-wave granularity. flag idx = ((bg*64+hg)*4 + epi_wave)
  // consumer wave w polls 32 flags: producers hg' = 8w..8w+7, epi waves 0..3
  unsigned int* myFlag = cnt + (size_t)(((((bg << 6) | hg) << 2) | wave)) * 64; // epi waves 0-3 only
  const int pl = lane & 31;
  const unsigned int* fp =
      cnt + (size_t)(((((bg << 6) | (wave << 3) | (pl >> 2)) << 2) | (pl & 3))) * 64;

  const unsigned short* xb = xT + (size_t)(b0 + l15) * 1024 + wave * 128 + l4 * 8;
  const unsigned short* hp = hbuf + (size_t)(b0 + l15) * 1024 + wave * 128 + l4 * 8;
  unsigned short* hw = hbuf + (size_t)(b0 + rb) * 1024 + (hg << 4) + cc;
  float* outp = out + (size_t)(b0 + rb) * 512 * 1024 + (hg << 4) + cc;
  float* sb = &slots[(wave * 4) * 320 + l15 * 20 + l4 * 4];

#pragma unroll 1
  for (int t = 0; t < 512; ++t) {
    const int par = t & 1;
    f32x4 a0 = {0.f, 0.f, 0.f, 0.f};
    f32x4 a1 = a0, a2 = a0, a3 = a0;

    // ---- x-part: 4 chunks from L2-cached xT (no cross-WG dependency).
    //      Runs between last step's flag publish and this step's poll ->
    //      covers producers' store-to-IC latency.
    {
      const unsigned short* xp = xb + (size_t)t * 65536;
      bf16x8 Ax[4];
#pragma unroll
      for (int kc = 0; kc < 4; ++kc) Ax[kc] = *(const bf16x8*)(xp + kc * 32);
#pragma unroll
      for (int kc = 0; kc < 4; ++kc) {
        a0 = __builtin_amdgcn_mfma_f32_16x16x32_bf16(Ax[kc], Bf[0][kc], a0, 0, 0, 0);
        a1 = __builtin_amdgcn_mfma_f32_16x16x32_bf16(Ax[kc], Bf[1][kc], a1, 0, 0, 0);
        a2 = __builtin_amdgcn_mfma_f32_16x16x32_bf16(Ax[kc], Bf[2][kc], a2, 0, 0, 0);
        a3 = __builtin_amdgcn_mfma_f32_16x16x32_bf16(Ax[kc], Bf[3][kc], a3, 0, 0, 0);
      }
    }

    // ---- pipelined 4-deep flag poll (discovery granularity ~200cy) ----
    if (t > 0 && !dead) {
      const unsigned int tgt = (unsigned int)t;
      asm volatile("s_waitcnt vmcnt(0)" ::: "memory");   // retire old stores: clean count
      unsigned v0, v1, v2, v3;
#define POLL_ISSUE(r)                                                     \
      asm volatile("global_load_dword %0, %1, off sc0 sc1"                \
                   : "=v"(r) : "v"(fp) : "memory")
      POLL_ISSUE(v0); asm volatile("s_sleep 1" ::: "memory");
      POLL_ISSUE(v1); asm volatile("s_sleep 1" ::: "memory");
      POLL_ISSUE(v2); asm volatile("s_sleep 1" ::: "memory");
      POLL_ISSUE(v3);
      long guard = 0;
      for (;;) {
        asm volatile("s_waitcnt vmcnt(3)" : "+v"(v0) :: "memory");
        if (__all((int)(v0 >= tgt))) break;
        POLL_ISSUE(v0); asm volatile("s_sleep 2" ::: "memory");
        asm volatile("s_waitcnt vmcnt(3)" : "+v"(v1) :: "memory");
        if (__all((int)(v1 >= tgt))) break;
        POLL_ISSUE(v1); asm volatile("s_sleep 2" ::: "memory");
        asm volatile("s_waitcnt vmcnt(3)" : "+v"(v2) :: "memory");
        if (__all((int)(v2 >= tgt))) break;
        POLL_ISSUE(v2); asm volatile("s_sleep 2" ::: "memory");
        asm volatile("s_waitcnt vmcnt(3)" : "+v"(v3) :: "memory");
        if (__all((int)(v3 >= tgt))) break;
        POLL_ISSUE(v3); asm volatile("s_sleep 2" ::: "memory");
        if ((guard += 4) > (1l << 20)) { dead = true; break; }  // fail fast
      }
#undef POLL_ISSUE
    }

    // ---- h-part: one-shot bypass load of my 4KB slice, then 16 MFMA ----
    // (issued after the poll observed flags>=t -> causally after h at IC)
    {
      const unsigned short* hq = hp + (size_t)par * 65536;
      union { i32x4 i; bf16x8 h; } Ah[4];
#pragma unroll
      for (int kc = 0; kc < 4; ++kc) {
        asm volatile("global_load_dwordx4 %0, %1, off sc0 sc1"
                     : "=v"(Ah[kc].i) : "v"(hq + kc * 32) : "memory");
      }
      asm volatile("s_waitcnt vmcnt(0)"
                   : "+v"(Ah[0].i), "+v"(Ah[1].i), "+v"(Ah[2].i), "+v"(Ah[3].i)
                   :: "memory");
#pragma unroll
      for (int kc = 0; kc < 4; ++kc) {
        a0 = __builtin_amdgcn_mfma_f32_16x16x32_bf16(Ah[kc].h, Bf[0][4 + kc], a0, 0, 0, 0);
        a1 = __builtin_amdgcn_mfma_f32_16x16x32_bf16(Ah[kc].h, Bf[1][4 + kc], a1, 0, 0, 0);
        a2 = __builtin_amdgcn_mfma_f32_16x16x32_bf16(Ah[kc].h, Bf[2][4 + kc], a2, 0, 0, 0);
        a3 = __builtin_amdgcn_mfma_f32_16x16x32_bf16(Ah[kc].h, Bf[3][4 + kc], a3, 0, 0, 0);
      }
    }

    *(f32x4*)(sb + 0)   = a0;
    *(f32x4*)(sb + 320) = a1;
    *(f32x4*)(sb + 640) = a2;
    *(f32x4*)(sb + 960) = a3;
    __syncthreads();   // barrier1: partials complete (orders ALL polls before epilogue)

    float hval = 0.f;
    if (tid < 256) {
      float Gi = bi, Gf = bff, Gg = bgg, Go = bo;
      const int base = cc * 20 + rb;
#pragma unroll
      for (int w = 0; w < 8; ++w) {
        Gi += slots[(w * 4 + 0) * 320 + base];
        Gf += slots[(w * 4 + 1) * 320 + base];
        Gg += slots[(w * 4 + 2) * 320 + base];
        Go += slots[(w * 4 + 3) * 320 + base];
      }
      // rcp-based sigmoid/tanh (v_rcp err ~1e-5 << bf16 noise)
      const float ig = __builtin_amdgcn_rcpf(1.f + __expf(-Gi));
      const float fg = __builtin_amdgcn_rcpf(1.f + __expf(-Gf));
      const float og = __builtin_amdgcn_rcpf(1.f + __expf(-Go));
      float ag = __builtin_fabsf(Gg);
      float eg = __expf(-2.f * ag);
      float tg = (1.f - eg) * __builtin_amdgcn_rcpf(1.f + eg);
      tg = (Gg < 0.f) ? -tg : tg;
      c_state = fg * c_state + ig * tg;
      float ac = __builtin_fabsf(c_state);
      float ec = __expf(-2.f * ac);
      float tc = (1.f - ec) * __builtin_amdgcn_rcpf(1.f + ec);
      tc = (c_state < 0.f) ? -tc : tc;
      hval = og * tc;
      // h(t+1) -> other parity slab, cache-bypass (visible at IC; no fence)
      unsigned int hbits = (unsigned int)f2bf(hval);
      asm volatile("global_store_short %0, %1, off sc0 sc1"
                   :: "v"(hw + (size_t)(par ^ 1) * 65536), "v"(hbits) : "memory");
      // per-wave drain + flag publish BEFORE barrier2 (off the barrier path)
      asm volatile("s_waitcnt vmcnt(0)" ::: "memory");
      if ((tid & 63) == 0) {
        asm volatile("global_store_dword %0, %1, off sc0 sc1"
                     :: "v"(myFlag), "v"((unsigned int)(t + 1)) : "memory");
      }
    }
    __syncthreads();   // barrier2: slots consumed, safe to overwrite next step

    if (tid < 256) {
      outp[(size_t)t * 1024] = hval;              // off critical path
      if (t == 511) {
        const size_t o2 = 33554432ull + (size_t)(b0 + rb) * 1024 + (hg << 4) + cc;
        out[o2] = hval;                           // h_T
        out[o2 + 65536] = c_state;                // c_T
      }
    }
  }
}

extern "C" void kernel_launch(void* const* d_in, const int* in_sizes, int n_in,
                              void* d_out, int out_size, void* d_ws, size_t ws_size,
                              hipStream_t stream) {
  const float* x = (const float*)d_in[0];   // (64,512,1024)
  const float* W = (const float*)d_in[1];   // (2048,4096)
  const float* b = (const float*)d_in[2];   // (4096,)
  float* out = (float*)d_out;
  char* ws = (char*)d_ws;
  if (ws_size < WS_NEED) return;            // need ~84.4 MB scratch

  unsigned short* xT = (unsigned short*)(ws + XT_OFF);
  unsigned short* WT = (unsigned short*)(ws + WT_OFF);
  unsigned short* hb = (unsigned short*)(ws + HB_OFF);
  unsigned int*  cn = (unsigned int*)(ws + CNT_OFF);

  hipLaunchKernelGGL(k_convert_x, dim3(32768), dim3(256), 0, stream, x, xT);
  hipLaunchKernelGGL(k_convert_W, dim3(2048),  dim3(256), 0, stream, W, WT);
  hipLaunchKernelGGL(k_init,      dim3(96),    dim3(256), 0, stream, hb, cn);

  // Launch-path hedge: cooperative launch skipped under stream capture,
  // plain-launch fallback on any error. Grid = 1 WG/CU x 256 CUs either way.
  void* kargs[] = { (void*)&xT, (void*)&WT, (void*)&b, (void*)&hb, (void*)&cn, (void*)&out };
  hipStreamCaptureStatus cap = hipStreamCaptureStatusNone;
  (void)hipStreamIsCapturing(stream, &cap);
  hipError_t lerr = hipErrorUnknown;
  if (cap == hipStreamCaptureStatusNone) {
    lerr = hipLaunchCooperativeKernel((void*)lstm_persistent, dim3(256), dim3(512),
                                      kargs, 0, stream);
  }
  if (lerr != hipSuccess) {
    hipLaunchKernelGGL(lstm_persistent, dim3(256), dim3(512), 0, stream,
                       xT, WT, b, hb, cn, out);
  }
}